// Round 8
// baseline (267.697 us; speedup 1.0000x reference)
//
#include <hip/hip_runtime.h>
#include <hip/hip_fp16.h>

#define N_NODES 100000
#define N_EDGES 1250000
#define F_RAW 48
#define F_LOC 16
#define F1 48
#define F_IN1 64   // F_RAW + F_LOC
#define F_IN2 64   // F1 + F_LOC
#define F_OUT 64

#define SCAN_SEG 1024
#define SCAN_NB ((N_NODES + SCAN_SEG - 1) / SCAN_SEG)  // 98
#define EHALF (N_EDGES / 2)

typedef _Float16 half8_t __attribute__((ext_vector_type(8)));
typedef float floatx4 __attribute__((ext_vector_type(4)));

// ---------------------------------------------------------------------------
// Edge-index dtype detection (int64 vs int32 buffer).
// ---------------------------------------------------------------------------
__global__ void k_detect(const unsigned* edges_u32, int* flag) {
    __shared__ int any;
    if (threadIdx.x == 0) any = 0;
    __syncthreads();
    int nz = 0;
    for (int i = threadIdx.x; i < 2048; i += 256) {
        if (edges_u32[2 * i + 1] != 0u) nz = 1;
    }
    if (nz) atomicOr(&any, 1);
    __syncthreads();
    if (threadIdx.x == 0) *flag = any;
}

__device__ __forceinline__ void load_edge(const void* edges, int is32, int e,
                                          int& s, int& d) {
    if (is32) {
        const int* p = (const int*)edges;
        s = p[e];
        d = p[N_EDGES + e];
    } else {
        const long long* p = (const long long*)edges;
        s = (int)p[e];
        d = (int)p[N_EDGES + e];
    }
}

// convert edges -> int32 src/dst arrays + degree histogram
__global__ void k_prep(const void* edges, const int* flag,
                       int* __restrict__ src32, int* __restrict__ dst32,
                       int* __restrict__ deg) {
    int e = blockIdx.x * blockDim.x + threadIdx.x;
    if (e >= N_EDGES) return;
    int s, d;
    load_edge(edges, *flag, e, s, d);
    src32[e] = s;
    dst32[e] = d;
    atomicAdd(&deg[d], 1);
}

// --------------------------- hierarchical scan ------------------------------
__global__ __launch_bounds__(256) void k_scan_part(const int* __restrict__ deg,
                                                   int* __restrict__ bsum) {
    int b = blockIdx.x;
    int t = threadIdx.x;
    int i0 = b * SCAN_SEG + t * 4;
    int s = 0;
#pragma unroll
    for (int j = 0; j < 4; ++j) {
        int i = i0 + j;
        if (i < N_NODES) s += deg[i];
    }
#pragma unroll
    for (int m = 1; m < 64; m <<= 1) s += __shfl_xor(s, m);
    __shared__ int ws[4];
    if ((t & 63) == 0) ws[t >> 6] = s;
    __syncthreads();
    if (t == 0) bsum[b] = ws[0] + ws[1] + ws[2] + ws[3];
}

__global__ __launch_bounds__(128) void k_scan_top(int* __restrict__ bsum,
                                                  int* __restrict__ rowptr) {
    __shared__ int sh[128];
    int t = threadIdx.x;
    int v = (t < SCAN_NB) ? bsum[t] : 0;
    sh[t] = v;
    __syncthreads();
    for (int off = 1; off < 128; off <<= 1) {
        int u = (t >= off) ? sh[t - off] : 0;
        __syncthreads();
        sh[t] += u;
        __syncthreads();
    }
    if (t < SCAN_NB) bsum[t] = (t == 0) ? 0 : sh[t - 1];
    if (t == 127) rowptr[N_NODES] = sh[127];
}

__global__ __launch_bounds__(256) void k_scan_down(
    const int* __restrict__ deg, const int* __restrict__ bsum,
    int* __restrict__ rowptr, int* __restrict__ cnt,
    float* __restrict__ dinv) {
    int b = blockIdx.x;
    int t = threadIdx.x;
    int lane = t & 63;
    int wave = t >> 6;
    int i0 = b * SCAN_SEG + t * 4;
    int v[4];
    int s = 0;
#pragma unroll
    for (int j = 0; j < 4; ++j) {
        int i = i0 + j;
        v[j] = (i < N_NODES) ? deg[i] : 0;
        s += v[j];
    }
    int x = s;
#pragma unroll
    for (int off = 1; off < 64; off <<= 1) {
        int u = __shfl_up(x, off);
        if (lane >= off) x += u;
    }
    __shared__ int ws[4];
    if (lane == 63) ws[wave] = x;
    __syncthreads();
    int woff = 0;
    for (int w = 0; w < wave; ++w) woff += ws[w];
    int run = bsum[b] + woff + (x - s);
#pragma unroll
    for (int j = 0; j < 4; ++j) {
        int i = i0 + j;
        if (i < N_NODES) {
            rowptr[i] = run;
            cnt[i] = run;
            dinv[i] = rsqrtf((float)v[j] + 1.0f);
            run += v[j];
        }
    }
}

// fill CSR: packed 4B entry = (src << 15) | fixed15(dinv[src]); 2 edges/thread
__global__ void k_fill(const int* __restrict__ src32,
                       const int* __restrict__ dst32,
                       const float* __restrict__ dinv, int* __restrict__ cnt,
                       unsigned* __restrict__ csr4) {
    int i = blockIdx.x * blockDim.x + threadIdx.x;
    if (i >= EHALF) return;
    int s0 = src32[i], d0 = dst32[i];
    int s1 = src32[i + EHALF], d1 = dst32[i + EHALF];
    float v0 = dinv[s0];
    float v1 = dinv[s1];
    int c0 = (int)(v0 * 32767.f + 0.5f);
    int c1 = (int)(v1 * 32767.f + 0.5f);
    int p0 = atomicAdd(&cnt[d0], 1);
    int p1 = atomicAdd(&cnt[d1], 1);
    csr4[p0] = ((unsigned)s0 << 15) | (unsigned)c0;
    csr4[p1] = ((unsigned)s1 << 15) | (unsigned)c1;
}

// ---------------------------------------------------------------------------
// x0 = concat(feat, loc) as fp16 rows of 64; thread per int4 (8 halves)
// ---------------------------------------------------------------------------
__global__ __launch_bounds__(256) void k_x0(const float* __restrict__ feat,
                                            const float* __restrict__ loc,
                                            __half* __restrict__ x0) {
    int idx = blockIdx.x * 256 + threadIdx.x;
    if (idx >= N_NODES * 8) return;
    int node = idx >> 3;
    int s = idx & 7;
    const float* srcp = (s < 6) ? feat + (size_t)node * F_RAW + s * 8
                                : loc + (size_t)node * F_LOC + (s - 6) * 8;
    float4 f0 = reinterpret_cast<const float4*>(srcp)[0];
    float4 f1 = reinterpret_cast<const float4*>(srcp)[1];
    __half2 q[4];
    q[0] = __halves2half2(__float2half(f0.x), __float2half(f0.y));
    q[1] = __halves2half2(__float2half(f0.z), __float2half(f0.w));
    q[2] = __halves2half2(__float2half(f1.x), __float2half(f1.y));
    q[3] = __halves2half2(__float2half(f1.z), __float2half(f1.w));
    reinterpret_cast<int4*>(x0)[idx] = *reinterpret_cast<int4*>(q);
}

// ---------------------------------------------------------------------------
// pack W [64][M] fp32 into MFMA B-fragment order, fp16.
// ---------------------------------------------------------------------------
__global__ void k_wprep(const float* __restrict__ W, __half* __restrict__ Wpk,
                        int M, int CT) {
    int lane = threadIdx.x;  // 64 threads
    for (int ct = 0; ct < CT; ++ct)
        for (int kt = 0; kt < 2; ++kt)
            for (int j = 0; j < 8; ++j) {
                int k = kt * 32 + (lane >> 4) * 8 + j;
                int c = ct * 16 + (lane & 15);
                Wpk[((ct * 2 + kt) * 64 + lane) * 8 + j] =
                    __float2half(W[k * M + c]);
            }
}

// ---------------------------------------------------------------------------
// Y = X @ W via mfma_f32_16x16x32_f16. 32 nodes/wave, CT col tiles, K=64.
// ---------------------------------------------------------------------------
template <int CT, int ZPAD>
__global__ __launch_bounds__(256) void k_gemm(const __half* __restrict__ X,
                                              const __half* __restrict__ Wpk,
                                              __half* __restrict__ Y) {
    int wid = threadIdx.x >> 6;
    int lane = threadIdx.x & 63;
    int nb = (blockIdx.x * 4 + wid) * 32;
    if (nb >= N_NODES) return;
    half8_t b[CT][2];
#pragma unroll
    for (int ct = 0; ct < CT; ++ct)
#pragma unroll
        for (int kt = 0; kt < 2; ++kt)
            b[ct][kt] =
                *reinterpret_cast<const half8_t*>(Wpk + ((ct * 2 + kt) * 64 + lane) * 8);
    int r = lane & 15;
    int ks = (lane >> 4) * 8;
    half8_t a[2][2];
#pragma unroll
    for (int rt = 0; rt < 2; ++rt)
#pragma unroll
        for (int kt = 0; kt < 2; ++kt)
            a[rt][kt] = *reinterpret_cast<const half8_t*>(
                X + ((size_t)(nb + rt * 16 + r) * 64 + kt * 32 + ks));
    floatx4 acc[2][CT];
#pragma unroll
    for (int rt = 0; rt < 2; ++rt)
#pragma unroll
        for (int ct = 0; ct < CT; ++ct) {
            floatx4 z = {0.f, 0.f, 0.f, 0.f};
            z = __builtin_amdgcn_mfma_f32_16x16x32_f16(a[rt][0], b[ct][0], z, 0, 0, 0);
            z = __builtin_amdgcn_mfma_f32_16x16x32_f16(a[rt][1], b[ct][1], z, 0, 0, 0);
            acc[rt][ct] = z;
        }
    int row0 = (lane >> 4) * 4;
    int col = lane & 15;
#pragma unroll
    for (int rt = 0; rt < 2; ++rt)
#pragma unroll
        for (int ct = 0; ct < CT; ++ct)
#pragma unroll
            for (int j = 0; j < 4; ++j) {
                int node = nb + rt * 16 + row0 + j;
                Y[(size_t)node * 64 + ct * 16 + col] = __float2half(acc[rt][ct][j]);
            }
    if (ZPAD) {
        int node = nb + (lane & 31);
        int slot = 6 + (lane >> 5);
        *reinterpret_cast<int4*>(Y + (size_t)node * 64 + slot * 8) =
            make_int4(0, 0, 0, 0);
    }
}

// ---------------------------------------------------------------------------
// gather helpers (fp16 rows of 64 halves, 8 groups x 8 lanes x int4)
// ---------------------------------------------------------------------------
__device__ __forceinline__ void fma8(const int4& p, float c, float a[8]) {
    const __half2* h = reinterpret_cast<const __half2*>(&p);
#pragma unroll
    for (int j = 0; j < 4; ++j) {
        float2 t = __half22float2(h[j]);
        a[2 * j] = fmaf(t.x, c, a[2 * j]);
        a[2 * j + 1] = fmaf(t.y, c, a[2 * j + 1]);
    }
}

__device__ __forceinline__ void red8(float a[8]) {
#pragma unroll
    for (int j = 0; j < 8; ++j) {
        a[j] += __shfl_xor(a[j], 8);
        a[j] += __shfl_xor(a[j], 16);
        a[j] += __shfl_xor(a[j], 32);
    }
}

#define COEF(ent) ((float)((ent) & 0x7FFFu) * (1.f / 32767.f))

// agg1: x1 = [relu(agg(h1)*di + h1*d2 + b1) (48) | loc (16)] as fp16 rows
__global__ __launch_bounds__(256) void k_agg1(
    const __half* __restrict__ h1h, const float* __restrict__ dinv,
    const int* __restrict__ rowptr, const unsigned* __restrict__ csr4,
    const float* __restrict__ loc, const float* __restrict__ b1,
    __half* __restrict__ x1h) {
    int wave = threadIdx.x >> 6;
    int lane = threadIdx.x & 63;
    int grp = lane >> 3;
    int l8 = lane & 7;
    int node = blockIdx.x * 4 + wave;
    if (node >= N_NODES) return;
    int r0 = rowptr[node], r1 = rowptr[node + 1];
    const int4* h1x = reinterpret_cast<const int4*>(h1h);
    float di = dinv[node];
    int4 hs = h1x[(size_t)node * 8 + l8];
    float a0[8], a1[8];
#pragma unroll
    for (int j = 0; j < 8; ++j) a0[j] = a1[j] = 0.f;
    int e = r0 + grp;
    while (e + 8 < r1) {
        unsigned A = csr4[e];
        unsigned B = csr4[e + 8];
        int4 vA = h1x[(size_t)(A >> 15) * 8 + l8];
        int4 vB = h1x[(size_t)(B >> 15) * 8 + l8];
        fma8(vA, COEF(A), a0);
        fma8(vB, COEF(B), a1);
        e += 16;
    }
    if (e < r1) {
        unsigned A = csr4[e];
        int4 vA = h1x[(size_t)(A >> 15) * 8 + l8];
        fma8(vA, COEF(A), a0);
    }
#pragma unroll
    for (int j = 0; j < 8; ++j) a0[j] += a1[j];
    red8(a0);
    if (lane < 8) {
        __half2 q[4];
        if (l8 < 6) {
            float d2 = di * di;
            const float4* b1v = reinterpret_cast<const float4*>(b1);
            float4 bA = b1v[l8 * 2];
            float4 bB = b1v[l8 * 2 + 1];
            float bb[8] = {bA.x, bA.y, bA.z, bA.w, bB.x, bB.y, bB.z, bB.w};
            const __half2* hh = reinterpret_cast<const __half2*>(&hs);
            float o[8];
#pragma unroll
            for (int j = 0; j < 4; ++j) {
                float2 t = __half22float2(hh[j]);
                o[2 * j] = fmaxf(fmaf(a0[2 * j], di, fmaf(t.x, d2, bb[2 * j])), 0.f);
                o[2 * j + 1] =
                    fmaxf(fmaf(a0[2 * j + 1], di, fmaf(t.y, d2, bb[2 * j + 1])), 0.f);
            }
#pragma unroll
            for (int j = 0; j < 4; ++j)
                q[j] = __halves2half2(__float2half(o[2 * j]), __float2half(o[2 * j + 1]));
        } else {
            const float* lp = loc + (size_t)node * F_LOC + (l8 - 6) * 8;
            float4 f0 = reinterpret_cast<const float4*>(lp)[0];
            float4 f1 = reinterpret_cast<const float4*>(lp)[1];
            q[0] = __halves2half2(__float2half(f0.x), __float2half(f0.y));
            q[1] = __halves2half2(__float2half(f0.z), __float2half(f0.w));
            q[2] = __halves2half2(__float2half(f1.x), __float2half(f1.y));
            q[3] = __halves2half2(__float2half(f1.z), __float2half(f1.w));
        }
        reinterpret_cast<int4*>(x1h)[(size_t)node * 8 + l8] =
            *reinterpret_cast<int4*>(q);
    }
}

// fused: agg2 (8-group fp16 gather) + self + bias -> out (fp32)
__global__ __launch_bounds__(256) void k_out(
    const __half* __restrict__ h2h, const float* __restrict__ dinv,
    const int* __restrict__ rowptr, const unsigned* __restrict__ csr4,
    const float* __restrict__ b2, float* __restrict__ out) {
    int wave = threadIdx.x >> 6;
    int lane = threadIdx.x & 63;
    int grp = lane >> 3;
    int l8 = lane & 7;
    int node = blockIdx.x * 4 + wave;
    if (node >= N_NODES) return;
    int r0 = rowptr[node], r1 = rowptr[node + 1];
    const int4* h2x = reinterpret_cast<const int4*>(h2h);
    float di = dinv[node];
    int4 hs = h2x[(size_t)node * 8 + l8];
    float a0[8], a1[8];
#pragma unroll
    for (int j = 0; j < 8; ++j) a0[j] = a1[j] = 0.f;
    int e = r0 + grp;
    while (e + 8 < r1) {
        unsigned A = csr4[e];
        unsigned B = csr4[e + 8];
        int4 vA = h2x[(size_t)(A >> 15) * 8 + l8];
        int4 vB = h2x[(size_t)(B >> 15) * 8 + l8];
        fma8(vA, COEF(A), a0);
        fma8(vB, COEF(B), a1);
        e += 16;
    }
    if (e < r1) {
        unsigned A = csr4[e];
        int4 vA = h2x[(size_t)(A >> 15) * 8 + l8];
        fma8(vA, COEF(A), a0);
    }
#pragma unroll
    for (int j = 0; j < 8; ++j) a0[j] += a1[j];
    red8(a0);
    if (lane < 8) {
        float d2 = di * di;
        const float4* b2v = reinterpret_cast<const float4*>(b2);
        float4 bA = b2v[l8 * 2];
        float4 bB = b2v[l8 * 2 + 1];
        float bb[8] = {bA.x, bA.y, bA.z, bA.w, bB.x, bB.y, bB.z, bB.w};
        const __half2* hh = reinterpret_cast<const __half2*>(&hs);
        float o[8];
#pragma unroll
        for (int j = 0; j < 4; ++j) {
            float2 t = __half22float2(hh[j]);
            o[2 * j] = fmaf(a0[2 * j], di, fmaf(t.x, d2, bb[2 * j]));
            o[2 * j + 1] = fmaf(a0[2 * j + 1], di, fmaf(t.y, d2, bb[2 * j + 1]));
        }
        float4* ov = reinterpret_cast<float4*>(out + (size_t)node * F_OUT);
        ov[l8 * 2] = make_float4(o[0], o[1], o[2], o[3]);
        ov[l8 * 2 + 1] = make_float4(o[4], o[5], o[6], o[7]);
    }
}

extern "C" void kernel_launch(void* const* d_in, const int* in_sizes, int n_in,
                              void* d_out, int out_size, void* d_ws,
                              size_t ws_size, hipStream_t stream) {
    const void* edges = d_in[0];
    const float* feat = (const float*)d_in[1];
    const float* loc = (const float*)d_in[2];
    const float* W1 = (const float*)d_in[3];
    const float* b1 = (const float*)d_in[4];
    const float* W2 = (const float*)d_in[5];
    const float* b2 = (const float*)d_in[6];
    float* out = (float*)d_out;

    char* ws = (char*)d_ws;
    float* dinv = (float*)(ws + 0);             //    400,000
    int* deg = (int*)(ws + 400000);             //    400,000
    int* rowptr = (int*)(ws + 800000);          //    400,016
    int* cnt = (int*)(ws + 1200016);            //    400,000
    int* src32 = (int*)(ws + 1600016);          //  5,000,000
    int* dst32 = (int*)(ws + 6600016);          //  5,000,000
    unsigned* csr4 = (unsigned*)(ws + 11600016);//  5,000,048
    __half* x0h = (__half*)(ws + 16600064);     // 12,800,000 (x1h aliases)
    __half* h1h = (__half*)(ws + 29400064);     // 12,800,000
    __half* h2h = (__half*)(ws + 42200064);     // 12,800,000
    __half* wpk1 = (__half*)(ws + 55000064);    //      6,144
    __half* wpk2 = (__half*)(ws + 55006272);    //      8,192
    int* flag = (int*)(ws + 55014464);          //          4
    int* bsum = (int*)(ws + 55014480);          //        392
    __half* x1h = x0h;  // safe: x0h last read by k_gemm<3,1>, before k_agg1

    k_detect<<<1, 256, 0, stream>>>((const unsigned*)edges, flag);
    hipMemsetAsync(deg, 0, (size_t)N_NODES * 4, stream);
    k_wprep<<<1, 64, 0, stream>>>(W1, wpk1, F1, 3);
    k_wprep<<<1, 64, 0, stream>>>(W2, wpk2, F_OUT, 4);
    k_x0<<<(N_NODES * 8 + 255) / 256, 256, 0, stream>>>(feat, loc, x0h);
    k_prep<<<(N_EDGES + 255) / 256, 256, 0, stream>>>(edges, flag, src32,
                                                      dst32, deg);
    k_scan_part<<<SCAN_NB, 256, 0, stream>>>(deg, bsum);
    k_scan_top<<<1, 128, 0, stream>>>(bsum, rowptr);
    k_scan_down<<<SCAN_NB, 256, 0, stream>>>(deg, bsum, rowptr, cnt, dinv);
    k_fill<<<(EHALF + 255) / 256, 256, 0, stream>>>(src32, dst32, dinv, cnt,
                                                    csr4);
    int gblocks = (N_NODES / 32 + 3) / 4;  // 782
    k_gemm<3, 1><<<gblocks, 256, 0, stream>>>(x0h, wpk1, h1h);
    k_agg1<<<(N_NODES + 3) / 4, 256, 0, stream>>>(h1h, dinv, rowptr, csr4,
                                                  loc, b1, x1h);
    k_gemm<4, 0><<<gblocks, 256, 0, stream>>>(x1h, wpk2, h2h);
    k_out<<<(N_NODES + 3) / 4, 256, 0, stream>>>(h2h, dinv, rowptr, csr4, b2,
                                                 out);
}

// Round 9
// 172.464 us; speedup vs baseline: 1.5522x; 1.5522x over previous
//
#include <hip/hip_runtime.h>
#include <hip/hip_fp16.h>

#define N_NODES 100000
#define N_EDGES 1250000
#define F_RAW 48
#define F_LOC 16
#define F1 48
#define F_IN1 64   // F_RAW + F_LOC
#define F_IN2 64   // F1 + F_LOC
#define F_OUT 64

#define NB_BIN 100                         // edge chunks
#define CHUNK (N_EDGES / NB_BIN)           // 12500
#define NBUK 391                           // ceil(N_NODES/256) dst buckets
#define NSCAN (NBUK * NB_BIN)              // 39100
#define NSCAN_PARTS ((NSCAN + 1023) / 1024)  // 39

typedef _Float16 half8_t __attribute__((ext_vector_type(8)));
typedef float floatx4 __attribute__((ext_vector_type(4)));

// ---------------------------------------------------------------------------
// Edge-index dtype detection (int64 vs int32 buffer).
// ---------------------------------------------------------------------------
__global__ void k_detect(const unsigned* edges_u32, int* flag) {
    __shared__ int any;
    if (threadIdx.x == 0) any = 0;
    __syncthreads();
    int nz = 0;
    for (int i = threadIdx.x; i < 2048; i += 256) {
        if (edges_u32[2 * i + 1] != 0u) nz = 1;
    }
    if (nz) atomicOr(&any, 1);
    __syncthreads();
    if (threadIdx.x == 0) *flag = any;
}

__device__ __forceinline__ void load_edge(const void* edges, int is32, int e,
                                          int& s, int& d) {
    if (is32) {
        const int* p = (const int*)edges;
        s = p[e];
        d = p[N_EDGES + e];
    } else {
        const long long* p = (const long long*)edges;
        s = (int)p[e];
        d = (int)p[N_EDGES + e];
    }
}

// ---------------------------------------------------------------------------
// pass A: edges -> src32/dst32 (sequential) + per-(bucket,block) histogram.
// No global atomics.
// ---------------------------------------------------------------------------
__global__ __launch_bounds__(1024) void k_prepA(const void* edges,
                                                const int* flag,
                                                int* __restrict__ src32,
                                                int* __restrict__ dst32,
                                                int* __restrict__ bhist) {
    __shared__ int hist[NBUK];
    int b = blockIdx.x, t = threadIdx.x;
    for (int k = t; k < NBUK; k += 1024) hist[k] = 0;
    __syncthreads();
    int is32 = *flag;
    int e0 = b * CHUNK;
    int e1 = e0 + CHUNK;
    for (int e = e0 + t; e < e1; e += 1024) {
        int s, d;
        load_edge(edges, is32, e, s, d);
        src32[e] = s;
        dst32[e] = d;
        atomicAdd(&hist[d >> 8], 1);
    }
    __syncthreads();
    for (int k = t; k < NBUK; k += 1024) bhist[k * NB_BIN + b] = hist[k];
}

// ---------------------------------------------------------------------------
// generalized exclusive scan over n ints (in-place), 3 kernels.
// ---------------------------------------------------------------------------
__global__ __launch_bounds__(256) void k_gscan_part(const int* __restrict__ in,
                                                    int* __restrict__ part,
                                                    int n) {
    int b = blockIdx.x, t = threadIdx.x;
    int i0 = b * 1024 + t * 4;
    int s = 0;
#pragma unroll
    for (int j = 0; j < 4; ++j) {
        int i = i0 + j;
        if (i < n) s += in[i];
    }
#pragma unroll
    for (int m = 1; m < 64; m <<= 1) s += __shfl_xor(s, m);
    __shared__ int ws[4];
    if ((t & 63) == 0) ws[t >> 6] = s;
    __syncthreads();
    if (t == 0) part[b] = ws[0] + ws[1] + ws[2] + ws[3];
}

__global__ __launch_bounds__(64) void k_gscan_top(int* __restrict__ part,
                                                  int nb) {
    int t = threadIdx.x;
    int v = (t < nb) ? part[t] : 0;
    int x = v;
#pragma unroll
    for (int off = 1; off < 64; off <<= 1) {
        int u = __shfl_up(x, off);
        if (t >= off) x += u;
    }
    if (t < nb) part[t] = x - v;  // exclusive
}

__global__ __launch_bounds__(256) void k_gscan_down(int* __restrict__ data,
                                                    const int* __restrict__ part,
                                                    int n) {
    int b = blockIdx.x, t = threadIdx.x;
    int lane = t & 63, wv = t >> 6;
    int i0 = b * 1024 + t * 4;
    int v[4];
    int s = 0;
#pragma unroll
    for (int j = 0; j < 4; ++j) {
        int i = i0 + j;
        v[j] = (i < n) ? data[i] : 0;
        s += v[j];
    }
    int x = s;
#pragma unroll
    for (int off = 1; off < 64; off <<= 1) {
        int u = __shfl_up(x, off);
        if (lane >= off) x += u;
    }
    __shared__ int ws[4];
    if (lane == 63) ws[wv] = x;
    __syncthreads();
    int woff = 0;
    for (int w = 0; w < wv; ++w) woff += ws[w];
    int run = part[b] + woff + (x - s);
#pragma unroll
    for (int j = 0; j < 4; ++j) {
        int i = i0 + j;
        if (i < n) {
            data[i] = run;
            run += v[j];
        }
    }
}

// ---------------------------------------------------------------------------
// pass C: place edges into bucket-clustered bins. LDS slot counters only.
// binned entry = (dstlocal << 17) | src
// ---------------------------------------------------------------------------
__global__ __launch_bounds__(1024) void k_place(const int* __restrict__ src32,
                                                const int* __restrict__ dst32,
                                                const int* __restrict__ bhist,
                                                unsigned* __restrict__ binned) {
    __shared__ int cnt[NBUK];
    int b = blockIdx.x, t = threadIdx.x;
    for (int k = t; k < NBUK; k += 1024) cnt[k] = bhist[k * NB_BIN + b];
    __syncthreads();
    int e0 = b * CHUNK;
    int e1 = e0 + CHUNK;
    for (int e = e0 + t; e < e1; e += 1024) {
        int s = src32[e];
        int d = dst32[e];
        int p = atomicAdd(&cnt[d >> 8], 1);
        binned[p] = ((unsigned)(d & 255) << 17) | (unsigned)s;
    }
}

// ---------------------------------------------------------------------------
// pass D1: one block per bucket (256 nodes). Local histogram -> dinv/rowptr,
// local scan -> node-ordered placement of src into csr4 (contiguous span).
// ---------------------------------------------------------------------------
__global__ __launch_bounds__(256) void k_bucket(
    const unsigned* __restrict__ binned, const int* __restrict__ bhist,
    float* __restrict__ dinv, int* __restrict__ rowptr,
    unsigned* __restrict__ csr4) {
    int k = blockIdx.x, t = threadIdx.x;
    int lane = t & 63, wv = t >> 6;
    __shared__ int ldeg[256];
    __shared__ int wcnt[256];
    __shared__ int ws4[4];
    int base = bhist[k * NB_BIN];
    int next = (k + 1 < NBUK) ? bhist[(k + 1) * NB_BIN] : N_EDGES;
    int len = next - base;
    ldeg[t] = 0;
    __syncthreads();
    for (int i = t; i < len; i += 256)
        atomicAdd(&ldeg[binned[base + i] >> 17], 1);
    __syncthreads();
    int degv = ldeg[t];
    int x = degv;
#pragma unroll
    for (int off = 1; off < 64; off <<= 1) {
        int u = __shfl_up(x, off);
        if (lane >= off) x += u;
    }
    if (lane == 63) ws4[wv] = x;
    __syncthreads();
    int woff = 0;
    for (int w = 0; w < wv; ++w) woff += ws4[w];
    int excl = woff + x - degv;
    int node = k * 256 + t;
    if (node < N_NODES) {
        dinv[node] = rsqrtf((float)degv + 1.0f);
        rowptr[node] = base + excl;
    }
    wcnt[t] = base + excl;
    __syncthreads();
    for (int i = t; i < len; i += 256) {
        unsigned ent = binned[base + i];
        int dl = ent >> 17;
        int p = atomicAdd(&wcnt[dl], 1);
        csr4[p] = ent & 0x1FFFFu;
    }
    if (k == 0 && t == 0) rowptr[N_NODES] = N_EDGES;
}

// ---------------------------------------------------------------------------
// pass D2: stamp coef: csr4[i] = (src<<15) | fixed15(dinv[src]); int4-wide.
// ---------------------------------------------------------------------------
__global__ __launch_bounds__(256) void k_coef(unsigned* __restrict__ csr4,
                                              const float* __restrict__ dinv) {
    int i = blockIdx.x * 256 + threadIdx.x;
    if (i >= N_EDGES / 4) return;
    uint4 v = reinterpret_cast<uint4*>(csr4)[i];
    v.x = (v.x << 15) | (unsigned)(dinv[v.x] * 32767.f + 0.5f);
    v.y = (v.y << 15) | (unsigned)(dinv[v.y] * 32767.f + 0.5f);
    v.z = (v.z << 15) | (unsigned)(dinv[v.z] * 32767.f + 0.5f);
    v.w = (v.w << 15) | (unsigned)(dinv[v.w] * 32767.f + 0.5f);
    reinterpret_cast<uint4*>(csr4)[i] = v;
}

// ---------------------------------------------------------------------------
// x0 = concat(feat, loc) as fp16 rows of 64; thread per int4 (8 halves)
// ---------------------------------------------------------------------------
__global__ __launch_bounds__(256) void k_x0(const float* __restrict__ feat,
                                            const float* __restrict__ loc,
                                            __half* __restrict__ x0) {
    int idx = blockIdx.x * 256 + threadIdx.x;
    if (idx >= N_NODES * 8) return;
    int node = idx >> 3;
    int s = idx & 7;
    const float* srcp = (s < 6) ? feat + (size_t)node * F_RAW + s * 8
                                : loc + (size_t)node * F_LOC + (s - 6) * 8;
    float4 f0 = reinterpret_cast<const float4*>(srcp)[0];
    float4 f1 = reinterpret_cast<const float4*>(srcp)[1];
    __half2 q[4];
    q[0] = __halves2half2(__float2half(f0.x), __float2half(f0.y));
    q[1] = __halves2half2(__float2half(f0.z), __float2half(f0.w));
    q[2] = __halves2half2(__float2half(f1.x), __float2half(f1.y));
    q[3] = __halves2half2(__float2half(f1.z), __float2half(f1.w));
    reinterpret_cast<int4*>(x0)[idx] = *reinterpret_cast<int4*>(q);
}

// ---------------------------------------------------------------------------
// pack W [64][M] fp32 into MFMA B-fragment order, fp16.
// ---------------------------------------------------------------------------
__global__ void k_wprep(const float* __restrict__ W, __half* __restrict__ Wpk,
                        int M, int CT) {
    int lane = threadIdx.x;  // 64 threads
    for (int ct = 0; ct < CT; ++ct)
        for (int kt = 0; kt < 2; ++kt)
            for (int j = 0; j < 8; ++j) {
                int k = kt * 32 + (lane >> 4) * 8 + j;
                int c = ct * 16 + (lane & 15);
                Wpk[((ct * 2 + kt) * 64 + lane) * 8 + j] =
                    __float2half(W[k * M + c]);
            }
}

// ---------------------------------------------------------------------------
// Y = X @ W via mfma_f32_16x16x32_f16. 32 nodes/wave, CT col tiles, K=64.
// ---------------------------------------------------------------------------
template <int CT, int ZPAD>
__global__ __launch_bounds__(256) void k_gemm(const __half* __restrict__ X,
                                              const __half* __restrict__ Wpk,
                                              __half* __restrict__ Y) {
    int wid = threadIdx.x >> 6;
    int lane = threadIdx.x & 63;
    int nb = (blockIdx.x * 4 + wid) * 32;
    if (nb >= N_NODES) return;
    half8_t b[CT][2];
#pragma unroll
    for (int ct = 0; ct < CT; ++ct)
#pragma unroll
        for (int kt = 0; kt < 2; ++kt)
            b[ct][kt] =
                *reinterpret_cast<const half8_t*>(Wpk + ((ct * 2 + kt) * 64 + lane) * 8);
    int r = lane & 15;
    int ks = (lane >> 4) * 8;
    half8_t a[2][2];
#pragma unroll
    for (int rt = 0; rt < 2; ++rt)
#pragma unroll
        for (int kt = 0; kt < 2; ++kt)
            a[rt][kt] = *reinterpret_cast<const half8_t*>(
                X + ((size_t)(nb + rt * 16 + r) * 64 + kt * 32 + ks));
    floatx4 acc[2][CT];
#pragma unroll
    for (int rt = 0; rt < 2; ++rt)
#pragma unroll
        for (int ct = 0; ct < CT; ++ct) {
            floatx4 z = {0.f, 0.f, 0.f, 0.f};
            z = __builtin_amdgcn_mfma_f32_16x16x32_f16(a[rt][0], b[ct][0], z, 0, 0, 0);
            z = __builtin_amdgcn_mfma_f32_16x16x32_f16(a[rt][1], b[ct][1], z, 0, 0, 0);
            acc[rt][ct] = z;
        }
    int row0 = (lane >> 4) * 4;
    int col = lane & 15;
#pragma unroll
    for (int rt = 0; rt < 2; ++rt)
#pragma unroll
        for (int ct = 0; ct < CT; ++ct)
#pragma unroll
            for (int j = 0; j < 4; ++j) {
                int node = nb + rt * 16 + row0 + j;
                Y[(size_t)node * 64 + ct * 16 + col] = __float2half(acc[rt][ct][j]);
            }
    if (ZPAD) {
        int node = nb + (lane & 31);
        int slot = 6 + (lane >> 5);
        *reinterpret_cast<int4*>(Y + (size_t)node * 64 + slot * 8) =
            make_int4(0, 0, 0, 0);
    }
}

// ---------------------------------------------------------------------------
// gather helpers (fp16 rows of 64 halves, 8 groups x 8 lanes x int4)
// ---------------------------------------------------------------------------
__device__ __forceinline__ void fma8(const int4& p, float c, float a[8]) {
    const __half2* h = reinterpret_cast<const __half2*>(&p);
#pragma unroll
    for (int j = 0; j < 4; ++j) {
        float2 t = __half22float2(h[j]);
        a[2 * j] = fmaf(t.x, c, a[2 * j]);
        a[2 * j + 1] = fmaf(t.y, c, a[2 * j + 1]);
    }
}

__device__ __forceinline__ void red8(float a[8]) {
#pragma unroll
    for (int j = 0; j < 8; ++j) {
        a[j] += __shfl_xor(a[j], 8);
        a[j] += __shfl_xor(a[j], 16);
        a[j] += __shfl_xor(a[j], 32);
    }
}

#define COEF(ent) ((float)((ent) & 0x7FFFu) * (1.f / 32767.f))

// agg1: x1 = [relu(agg(h1)*di + h1*d2 + b1) (48) | loc (16)] as fp16 rows
__global__ __launch_bounds__(256) void k_agg1(
    const __half* __restrict__ h1h, const float* __restrict__ dinv,
    const int* __restrict__ rowptr, const unsigned* __restrict__ csr4,
    const float* __restrict__ loc, const float* __restrict__ b1,
    __half* __restrict__ x1h) {
    int wave = threadIdx.x >> 6;
    int lane = threadIdx.x & 63;
    int grp = lane >> 3;
    int l8 = lane & 7;
    int node = blockIdx.x * 4 + wave;
    if (node >= N_NODES) return;
    int r0 = rowptr[node], r1 = rowptr[node + 1];
    const int4* h1x = reinterpret_cast<const int4*>(h1h);
    float di = dinv[node];
    int4 hs = h1x[(size_t)node * 8 + l8];
    float a0[8], a1[8];
#pragma unroll
    for (int j = 0; j < 8; ++j) a0[j] = a1[j] = 0.f;
    int e = r0 + grp;
    while (e + 8 < r1) {
        unsigned A = csr4[e];
        unsigned B = csr4[e + 8];
        int4 vA = h1x[(size_t)(A >> 15) * 8 + l8];
        int4 vB = h1x[(size_t)(B >> 15) * 8 + l8];
        fma8(vA, COEF(A), a0);
        fma8(vB, COEF(B), a1);
        e += 16;
    }
    if (e < r1) {
        unsigned A = csr4[e];
        int4 vA = h1x[(size_t)(A >> 15) * 8 + l8];
        fma8(vA, COEF(A), a0);
    }
#pragma unroll
    for (int j = 0; j < 8; ++j) a0[j] += a1[j];
    red8(a0);
    if (lane < 8) {
        __half2 q[4];
        if (l8 < 6) {
            float d2 = di * di;
            const float4* b1v = reinterpret_cast<const float4*>(b1);
            float4 bA = b1v[l8 * 2];
            float4 bB = b1v[l8 * 2 + 1];
            float bb[8] = {bA.x, bA.y, bA.z, bA.w, bB.x, bB.y, bB.z, bB.w};
            const __half2* hh = reinterpret_cast<const __half2*>(&hs);
            float o[8];
#pragma unroll
            for (int j = 0; j < 4; ++j) {
                float2 t = __half22float2(hh[j]);
                o[2 * j] = fmaxf(fmaf(a0[2 * j], di, fmaf(t.x, d2, bb[2 * j])), 0.f);
                o[2 * j + 1] =
                    fmaxf(fmaf(a0[2 * j + 1], di, fmaf(t.y, d2, bb[2 * j + 1])), 0.f);
            }
#pragma unroll
            for (int j = 0; j < 4; ++j)
                q[j] = __halves2half2(__float2half(o[2 * j]), __float2half(o[2 * j + 1]));
        } else {
            const float* lp = loc + (size_t)node * F_LOC + (l8 - 6) * 8;
            float4 f0 = reinterpret_cast<const float4*>(lp)[0];
            float4 f1 = reinterpret_cast<const float4*>(lp)[1];
            q[0] = __halves2half2(__float2half(f0.x), __float2half(f0.y));
            q[1] = __halves2half2(__float2half(f0.z), __float2half(f0.w));
            q[2] = __halves2half2(__float2half(f1.x), __float2half(f1.y));
            q[3] = __halves2half2(__float2half(f1.z), __float2half(f1.w));
        }
        reinterpret_cast<int4*>(x1h)[(size_t)node * 8 + l8] =
            *reinterpret_cast<int4*>(q);
    }
}

// fused: agg2 (8-group fp16 gather) + self + bias -> out (fp32)
__global__ __launch_bounds__(256) void k_out(
    const __half* __restrict__ h2h, const float* __restrict__ dinv,
    const int* __restrict__ rowptr, const unsigned* __restrict__ csr4,
    const float* __restrict__ b2, float* __restrict__ out) {
    int wave = threadIdx.x >> 6;
    int lane = threadIdx.x & 63;
    int grp = lane >> 3;
    int l8 = lane & 7;
    int node = blockIdx.x * 4 + wave;
    if (node >= N_NODES) return;
    int r0 = rowptr[node], r1 = rowptr[node + 1];
    const int4* h2x = reinterpret_cast<const int4*>(h2h);
    float di = dinv[node];
    int4 hs = h2x[(size_t)node * 8 + l8];
    float a0[8], a1[8];
#pragma unroll
    for (int j = 0; j < 8; ++j) a0[j] = a1[j] = 0.f;
    int e = r0 + grp;
    while (e + 8 < r1) {
        unsigned A = csr4[e];
        unsigned B = csr4[e + 8];
        int4 vA = h2x[(size_t)(A >> 15) * 8 + l8];
        int4 vB = h2x[(size_t)(B >> 15) * 8 + l8];
        fma8(vA, COEF(A), a0);
        fma8(vB, COEF(B), a1);
        e += 16;
    }
    if (e < r1) {
        unsigned A = csr4[e];
        int4 vA = h2x[(size_t)(A >> 15) * 8 + l8];
        fma8(vA, COEF(A), a0);
    }
#pragma unroll
    for (int j = 0; j < 8; ++j) a0[j] += a1[j];
    red8(a0);
    if (lane < 8) {
        float d2 = di * di;
        const float4* b2v = reinterpret_cast<const float4*>(b2);
        float4 bA = b2v[l8 * 2];
        float4 bB = b2v[l8 * 2 + 1];
        float bb[8] = {bA.x, bA.y, bA.z, bA.w, bB.x, bB.y, bB.z, bB.w};
        const __half2* hh = reinterpret_cast<const __half2*>(&hs);
        float o[8];
#pragma unroll
        for (int j = 0; j < 4; ++j) {
            float2 t = __half22float2(hh[j]);
            o[2 * j] = fmaf(a0[2 * j], di, fmaf(t.x, d2, bb[2 * j]));
            o[2 * j + 1] = fmaf(a0[2 * j + 1], di, fmaf(t.y, d2, bb[2 * j + 1]));
        }
        float4* ov = reinterpret_cast<float4*>(out + (size_t)node * F_OUT);
        ov[l8 * 2] = make_float4(o[0], o[1], o[2], o[3]);
        ov[l8 * 2 + 1] = make_float4(o[4], o[5], o[6], o[7]);
    }
}

extern "C" void kernel_launch(void* const* d_in, const int* in_sizes, int n_in,
                              void* d_out, int out_size, void* d_ws,
                              size_t ws_size, hipStream_t stream) {
    const void* edges = d_in[0];
    const float* feat = (const float*)d_in[1];
    const float* loc = (const float*)d_in[2];
    const float* W1 = (const float*)d_in[3];
    const float* b1 = (const float*)d_in[4];
    const float* W2 = (const float*)d_in[5];
    const float* b2 = (const float*)d_in[6];
    float* out = (float*)d_out;

    char* ws = (char*)d_ws;
    float* dinv = (float*)(ws + 0);               //    400,000
    int* rowptr = (int*)(ws + 400000);            //    400,016
    int* src32 = (int*)(ws + 800016);             //  5,000,000
    int* dst32 = (int*)(ws + 5800016);            //  5,000,000
    int* bhist = (int*)(ws + 10800016);           //    156,400
    int* bsum = (int*)(ws + 10956416);            //        256
    unsigned* binned = (unsigned*)(ws + 10956672);//  5,000,000
    unsigned* csr4 = (unsigned*)(ws + 15956672);  //  5,000,000
    __half* x0h = (__half*)(ws + 20956672);       // 12,800,000 (x1h aliases)
    __half* h1h = (__half*)(ws + 33756672);       // 12,800,000
    __half* h2h = (__half*)(ws + 46556672);       // 12,800,000
    __half* wpk1 = (__half*)(ws + 59356672);      //      6,144
    __half* wpk2 = (__half*)(ws + 59362816);      //      8,192
    int* flag = (int*)(ws + 59371008);            //          4
    __half* x1h = x0h;  // safe: x0h last read by k_gemm<3,1>, before k_agg1

    k_detect<<<1, 256, 0, stream>>>((const unsigned*)edges, flag);
    k_wprep<<<1, 64, 0, stream>>>(W1, wpk1, F1, 3);
    k_wprep<<<1, 64, 0, stream>>>(W2, wpk2, F_OUT, 4);
    k_x0<<<(N_NODES * 8 + 255) / 256, 256, 0, stream>>>(feat, loc, x0h);

    // ---- CSR build: scatter-free two-level counting sort ----
    k_prepA<<<NB_BIN, 1024, 0, stream>>>(edges, flag, src32, dst32, bhist);
    k_gscan_part<<<NSCAN_PARTS, 256, 0, stream>>>(bhist, bsum, NSCAN);
    k_gscan_top<<<1, 64, 0, stream>>>(bsum, NSCAN_PARTS);
    k_gscan_down<<<NSCAN_PARTS, 256, 0, stream>>>(bhist, bsum, NSCAN);
    k_place<<<NB_BIN, 1024, 0, stream>>>(src32, dst32, bhist, binned);
    k_bucket<<<NBUK, 256, 0, stream>>>(binned, bhist, dinv, rowptr, csr4);
    k_coef<<<(N_EDGES / 4 + 255) / 256, 256, 0, stream>>>(csr4, dinv);

    // ---- GEMMs + aggregations ----
    int gblocks = (N_NODES / 32 + 3) / 4;  // 782
    k_gemm<3, 1><<<gblocks, 256, 0, stream>>>(x0h, wpk1, h1h);
    k_agg1<<<(N_NODES + 3) / 4, 256, 0, stream>>>(h1h, dinv, rowptr, csr4,
                                                  loc, b1, x1h);
    k_gemm<4, 0><<<gblocks, 256, 0, stream>>>(x1h, wpk2, h2h);
    k_out<<<(N_NODES + 3) / 4, 256, 0, stream>>>(h2h, dinv, rowptr, csr4, b2,
                                                 out);
}

// Round 10
// 165.789 us; speedup vs baseline: 1.6147x; 1.0403x over previous
//
#include <hip/hip_runtime.h>
#include <hip/hip_fp16.h>

#define N_NODES 100000
#define N_EDGES 1250000
#define F_RAW 48
#define F_LOC 16
#define F1 48
#define F_IN1 64   // F_RAW + F_LOC
#define F_IN2 64   // F1 + F_LOC
#define F_OUT 64

#define NB_BIN 100                         // edge chunks
#define CHUNK (N_EDGES / NB_BIN)           // 12500
#define NBUK 391                           // ceil(N_NODES/256) dst buckets
#define NSCAN (NBUK * NB_BIN)              // 39100
#define NSCAN_PARTS ((NSCAN + 1023) / 1024)  // 39

typedef _Float16 half8_t __attribute__((ext_vector_type(8)));
typedef float floatx4 __attribute__((ext_vector_type(4)));

// ---------------------------------------------------------------------------
// Edge-index dtype detection (int64 vs int32 buffer).
// ---------------------------------------------------------------------------
__global__ void k_detect(const unsigned* edges_u32, int* flag) {
    __shared__ int any;
    if (threadIdx.x == 0) any = 0;
    __syncthreads();
    int nz = 0;
    for (int i = threadIdx.x; i < 2048; i += 256) {
        if (edges_u32[2 * i + 1] != 0u) nz = 1;
    }
    if (nz) atomicOr(&any, 1);
    __syncthreads();
    if (threadIdx.x == 0) *flag = any;
}

__device__ __forceinline__ void load_edge(const void* edges, int is32, int e,
                                          int& s, int& d) {
    if (is32) {
        const int* p = (const int*)edges;
        s = p[e];
        d = p[N_EDGES + e];
    } else {
        const long long* p = (const long long*)edges;
        s = (int)p[e];
        d = (int)p[N_EDGES + e];
    }
}

// ---------------------------------------------------------------------------
// pass A: edges -> src32/dst32 (sequential) + per-(bucket,block) histogram.
// ---------------------------------------------------------------------------
__global__ __launch_bounds__(1024) void k_prepA(const void* edges,
                                                const int* flag,
                                                int* __restrict__ src32,
                                                int* __restrict__ dst32,
                                                int* __restrict__ bhist) {
    __shared__ int hist[NBUK];
    int b = blockIdx.x, t = threadIdx.x;
    for (int k = t; k < NBUK; k += 1024) hist[k] = 0;
    __syncthreads();
    int is32 = *flag;
    int e0 = b * CHUNK;
    int e1 = e0 + CHUNK;
    for (int e = e0 + t; e < e1; e += 1024) {
        int s, d;
        load_edge(edges, is32, e, s, d);
        src32[e] = s;
        dst32[e] = d;
        atomicAdd(&hist[d >> 8], 1);
    }
    __syncthreads();
    for (int k = t; k < NBUK; k += 1024) bhist[k * NB_BIN + b] = hist[k];
}

// ---------------------------------------------------------------------------
// generalized exclusive scan over n ints (in-place), 3 kernels.
// ---------------------------------------------------------------------------
__global__ __launch_bounds__(256) void k_gscan_part(const int* __restrict__ in,
                                                    int* __restrict__ part,
                                                    int n) {
    int b = blockIdx.x, t = threadIdx.x;
    int i0 = b * 1024 + t * 4;
    int s = 0;
#pragma unroll
    for (int j = 0; j < 4; ++j) {
        int i = i0 + j;
        if (i < n) s += in[i];
    }
#pragma unroll
    for (int m = 1; m < 64; m <<= 1) s += __shfl_xor(s, m);
    __shared__ int ws[4];
    if ((t & 63) == 0) ws[t >> 6] = s;
    __syncthreads();
    if (t == 0) part[b] = ws[0] + ws[1] + ws[2] + ws[3];
}

__global__ __launch_bounds__(64) void k_gscan_top(int* __restrict__ part,
                                                  int nb) {
    int t = threadIdx.x;
    int v = (t < nb) ? part[t] : 0;
    int x = v;
#pragma unroll
    for (int off = 1; off < 64; off <<= 1) {
        int u = __shfl_up(x, off);
        if (t >= off) x += u;
    }
    if (t < nb) part[t] = x - v;  // exclusive
}

__global__ __launch_bounds__(256) void k_gscan_down(int* __restrict__ data,
                                                    const int* __restrict__ part,
                                                    int n) {
    int b = blockIdx.x, t = threadIdx.x;
    int lane = t & 63, wv = t >> 6;
    int i0 = b * 1024 + t * 4;
    int v[4];
    int s = 0;
#pragma unroll
    for (int j = 0; j < 4; ++j) {
        int i = i0 + j;
        v[j] = (i < n) ? data[i] : 0;
        s += v[j];
    }
    int x = s;
#pragma unroll
    for (int off = 1; off < 64; off <<= 1) {
        int u = __shfl_up(x, off);
        if (lane >= off) x += u;
    }
    __shared__ int ws[4];
    if (lane == 63) ws[wv] = x;
    __syncthreads();
    int woff = 0;
    for (int w = 0; w < wv; ++w) woff += ws[w];
    int run = part[b] + woff + (x - s);
#pragma unroll
    for (int j = 0; j < 4; ++j) {
        int i = i0 + j;
        if (i < n) {
            data[i] = run;
            run += v[j];
        }
    }
}

// ---------------------------------------------------------------------------
// pass C: place edges into bucket-clustered bins. LDS slot counters only.
// binned entry = (dstlocal << 17) | src
// ---------------------------------------------------------------------------
__global__ __launch_bounds__(1024) void k_place(const int* __restrict__ src32,
                                                const int* __restrict__ dst32,
                                                const int* __restrict__ bhist,
                                                unsigned* __restrict__ binned) {
    __shared__ int cnt[NBUK];
    int b = blockIdx.x, t = threadIdx.x;
    for (int k = t; k < NBUK; k += 1024) cnt[k] = bhist[k * NB_BIN + b];
    __syncthreads();
    int e0 = b * CHUNK;
    int e1 = e0 + CHUNK;
    for (int e = e0 + t; e < e1; e += 1024) {
        int s = src32[e];
        int d = dst32[e];
        int p = atomicAdd(&cnt[d >> 8], 1);
        binned[p] = ((unsigned)(d & 255) << 17) | (unsigned)s;
    }
}

// ---------------------------------------------------------------------------
// pass D1: one block per bucket (256 nodes): dinv/rowptr + node-ordered csr4.
// ---------------------------------------------------------------------------
__global__ __launch_bounds__(256) void k_bucket(
    const unsigned* __restrict__ binned, const int* __restrict__ bhist,
    float* __restrict__ dinv, int* __restrict__ rowptr,
    unsigned* __restrict__ csr4) {
    int k = blockIdx.x, t = threadIdx.x;
    int lane = t & 63, wv = t >> 6;
    __shared__ int ldeg[256];
    __shared__ int wcnt[256];
    __shared__ int ws4[4];
    int base = bhist[k * NB_BIN];
    int next = (k + 1 < NBUK) ? bhist[(k + 1) * NB_BIN] : N_EDGES;
    int len = next - base;
    ldeg[t] = 0;
    __syncthreads();
    for (int i = t; i < len; i += 256)
        atomicAdd(&ldeg[binned[base + i] >> 17], 1);
    __syncthreads();
    int degv = ldeg[t];
    int x = degv;
#pragma unroll
    for (int off = 1; off < 64; off <<= 1) {
        int u = __shfl_up(x, off);
        if (lane >= off) x += u;
    }
    if (lane == 63) ws4[wv] = x;
    __syncthreads();
    int woff = 0;
    for (int w = 0; w < wv; ++w) woff += ws4[w];
    int excl = woff + x - degv;
    int node = k * 256 + t;
    if (node < N_NODES) {
        dinv[node] = rsqrtf((float)degv + 1.0f);
        rowptr[node] = base + excl;
    }
    wcnt[t] = base + excl;
    __syncthreads();
    for (int i = t; i < len; i += 256) {
        unsigned ent = binned[base + i];
        int dl = ent >> 17;
        int p = atomicAdd(&wcnt[dl], 1);
        csr4[p] = ent & 0x1FFFFu;
    }
    if (k == 0 && t == 0) rowptr[N_NODES] = N_EDGES;
}

// ---------------------------------------------------------------------------
// pass D2: stamp coef: csr4[i] = (src<<14) | fp16bits(dinv[src]); int4-wide.
// dinv <= 1.0 so fp16 bits <= 0x3C00 (fits 14 bits).
// ---------------------------------------------------------------------------
__global__ __launch_bounds__(256) void k_coef(unsigned* __restrict__ csr4,
                                              const float* __restrict__ dinv) {
    int i = blockIdx.x * 256 + threadIdx.x;
    if (i >= N_EDGES / 4) return;
    uint4 v = reinterpret_cast<uint4*>(csr4)[i];
    v.x = (v.x << 14) | (unsigned)__half_as_ushort(__float2half(dinv[v.x]));
    v.y = (v.y << 14) | (unsigned)__half_as_ushort(__float2half(dinv[v.y]));
    v.z = (v.z << 14) | (unsigned)__half_as_ushort(__float2half(dinv[v.z]));
    v.w = (v.w << 14) | (unsigned)__half_as_ushort(__float2half(dinv[v.w]));
    reinterpret_cast<uint4*>(csr4)[i] = v;
}

// ---------------------------------------------------------------------------
// x0 = concat(feat, loc) as fp16 rows of 64; thread per int4 (8 halves)
// ---------------------------------------------------------------------------
__global__ __launch_bounds__(256) void k_x0(const float* __restrict__ feat,
                                            const float* __restrict__ loc,
                                            __half* __restrict__ x0) {
    int idx = blockIdx.x * 256 + threadIdx.x;
    if (idx >= N_NODES * 8) return;
    int node = idx >> 3;
    int s = idx & 7;
    const float* srcp = (s < 6) ? feat + (size_t)node * F_RAW + s * 8
                                : loc + (size_t)node * F_LOC + (s - 6) * 8;
    float4 f0 = reinterpret_cast<const float4*>(srcp)[0];
    float4 f1 = reinterpret_cast<const float4*>(srcp)[1];
    __half2 q[4];
    q[0] = __halves2half2(__float2half(f0.x), __float2half(f0.y));
    q[1] = __halves2half2(__float2half(f0.z), __float2half(f0.w));
    q[2] = __halves2half2(__float2half(f1.x), __float2half(f1.y));
    q[3] = __halves2half2(__float2half(f1.z), __float2half(f1.w));
    reinterpret_cast<int4*>(x0)[idx] = *reinterpret_cast<int4*>(q);
}

// ---------------------------------------------------------------------------
// pack W [64][M] fp32 into MFMA B-fragment order, fp16.
// ---------------------------------------------------------------------------
__global__ void k_wprep(const float* __restrict__ W, __half* __restrict__ Wpk,
                        int M, int CT) {
    int lane = threadIdx.x;  // 64 threads
    for (int ct = 0; ct < CT; ++ct)
        for (int kt = 0; kt < 2; ++kt)
            for (int j = 0; j < 8; ++j) {
                int k = kt * 32 + (lane >> 4) * 8 + j;
                int c = ct * 16 + (lane & 15);
                Wpk[((ct * 2 + kt) * 64 + lane) * 8 + j] =
                    __float2half(W[k * M + c]);
            }
}

// ---------------------------------------------------------------------------
// Y = X @ W via mfma_f32_16x16x32_f16. 32 nodes/wave, CT col tiles, K=64.
// ---------------------------------------------------------------------------
template <int CT, int ZPAD>
__global__ __launch_bounds__(256) void k_gemm(const __half* __restrict__ X,
                                              const __half* __restrict__ Wpk,
                                              __half* __restrict__ Y) {
    int wid = threadIdx.x >> 6;
    int lane = threadIdx.x & 63;
    int nb = (blockIdx.x * 4 + wid) * 32;
    if (nb >= N_NODES) return;
    half8_t b[CT][2];
#pragma unroll
    for (int ct = 0; ct < CT; ++ct)
#pragma unroll
        for (int kt = 0; kt < 2; ++kt)
            b[ct][kt] =
                *reinterpret_cast<const half8_t*>(Wpk + ((ct * 2 + kt) * 64 + lane) * 8);
    int r = lane & 15;
    int ks = (lane >> 4) * 8;
    half8_t a[2][2];
#pragma unroll
    for (int rt = 0; rt < 2; ++rt)
#pragma unroll
        for (int kt = 0; kt < 2; ++kt)
            a[rt][kt] = *reinterpret_cast<const half8_t*>(
                X + ((size_t)(nb + rt * 16 + r) * 64 + kt * 32 + ks));
    floatx4 acc[2][CT];
#pragma unroll
    for (int rt = 0; rt < 2; ++rt)
#pragma unroll
        for (int ct = 0; ct < CT; ++ct) {
            floatx4 z = {0.f, 0.f, 0.f, 0.f};
            z = __builtin_amdgcn_mfma_f32_16x16x32_f16(a[rt][0], b[ct][0], z, 0, 0, 0);
            z = __builtin_amdgcn_mfma_f32_16x16x32_f16(a[rt][1], b[ct][1], z, 0, 0, 0);
            acc[rt][ct] = z;
        }
    int row0 = (lane >> 4) * 4;
    int col = lane & 15;
#pragma unroll
    for (int rt = 0; rt < 2; ++rt)
#pragma unroll
        for (int ct = 0; ct < CT; ++ct)
#pragma unroll
            for (int j = 0; j < 4; ++j) {
                int node = nb + rt * 16 + row0 + j;
                Y[(size_t)node * 64 + ct * 16 + col] = __float2half(acc[rt][ct][j]);
            }
    if (ZPAD) {
        int node = nb + (lane & 31);
        int slot = 6 + (lane >> 5);
        *reinterpret_cast<int4*>(Y + (size_t)node * 64 + slot * 8) =
            make_int4(0, 0, 0, 0);
    }
}

// ---------------------------------------------------------------------------
// gather helpers: fp16 packed accumulate (v_pk_fma_f16)
// ---------------------------------------------------------------------------
__device__ __forceinline__ __half2 c2_from(unsigned A) {
    unsigned b = A & 0x3FFFu;
    unsigned p = b | (b << 16);
    return *reinterpret_cast<__half2*>(&p);
}

__device__ __forceinline__ void fma8h(const int4& p, __half2 c2, __half2 a[4]) {
    const __half2* h = reinterpret_cast<const __half2*>(&p);
#pragma unroll
    for (int j = 0; j < 4; ++j) a[j] = __hfma2(h[j], c2, a[j]);
}

__device__ __forceinline__ __half2 shfl_xor_h2(__half2 v, int m) {
    int i = *reinterpret_cast<int*>(&v);
    i = __shfl_xor(i, m);
    return *reinterpret_cast<__half2*>(&i);
}

// agg1: x1 = [relu(agg(h1)*di + h1*d2 + b1) (48) | loc (16)] as fp16 rows
__global__ __launch_bounds__(256) void k_agg1(
    const __half* __restrict__ h1h, const float* __restrict__ dinv,
    const int* __restrict__ rowptr, const unsigned* __restrict__ csr4,
    const float* __restrict__ loc, const float* __restrict__ b1,
    __half* __restrict__ x1h) {
    int wave = threadIdx.x >> 6;
    int lane = threadIdx.x & 63;
    int grp = lane >> 3;
    int l8 = lane & 7;
    int node = blockIdx.x * 4 + wave;
    if (node >= N_NODES) return;
    int r0 = rowptr[node], r1 = rowptr[node + 1];
    const char* h1c = reinterpret_cast<const char*>(h1h);
    float di = dinv[node];
    int4 hs = *reinterpret_cast<const int4*>(h1c + ((size_t)node << 7) + (l8 << 4));
    int len = r1 - r0;
    int L = (len + 7) >> 3;
    int gs = r0 + grp * L;
    int ge = gs + L;
    if (ge > r1) ge = r1;
    __half2 z2 = __float2half2_rn(0.f);
    __half2 a0[4] = {z2, z2, z2, z2};
    __half2 a1[4] = {z2, z2, z2, z2};
    int e = gs;
    for (; e + 1 < ge; e += 2) {
        unsigned A = csr4[e];
        unsigned B = csr4[e + 1];
        int4 vA = *reinterpret_cast<const int4*>(h1c + ((A >> 14) << 7) + (l8 << 4));
        int4 vB = *reinterpret_cast<const int4*>(h1c + ((B >> 14) << 7) + (l8 << 4));
        fma8h(vA, c2_from(A), a0);
        fma8h(vB, c2_from(B), a1);
    }
    if (e < ge) {
        unsigned A = csr4[e];
        int4 vA = *reinterpret_cast<const int4*>(h1c + ((A >> 14) << 7) + (l8 << 4));
        fma8h(vA, c2_from(A), a0);
    }
#pragma unroll
    for (int j = 0; j < 4; ++j) a0[j] = __hadd2(a0[j], a1[j]);
#pragma unroll
    for (int j = 0; j < 4; ++j) {
        a0[j] = __hadd2(a0[j], shfl_xor_h2(a0[j], 8));
        a0[j] = __hadd2(a0[j], shfl_xor_h2(a0[j], 16));
        a0[j] = __hadd2(a0[j], shfl_xor_h2(a0[j], 32));
    }
    if (lane < 8) {
        __half2 q[4];
        if (l8 < 6) {
            float d2 = di * di;
            const float4* b1v = reinterpret_cast<const float4*>(b1);
            float4 bA = b1v[l8 * 2];
            float4 bB = b1v[l8 * 2 + 1];
            float bb[8] = {bA.x, bA.y, bA.z, bA.w, bB.x, bB.y, bB.z, bB.w};
            const __half2* hh = reinterpret_cast<const __half2*>(&hs);
            float o[8];
#pragma unroll
            for (int j = 0; j < 4; ++j) {
                float2 t = __half22float2(hh[j]);
                float2 ag = __half22float2(a0[j]);
                o[2 * j] = fmaxf(fmaf(ag.x, di, fmaf(t.x, d2, bb[2 * j])), 0.f);
                o[2 * j + 1] =
                    fmaxf(fmaf(ag.y, di, fmaf(t.y, d2, bb[2 * j + 1])), 0.f);
            }
#pragma unroll
            for (int j = 0; j < 4; ++j)
                q[j] = __halves2half2(__float2half(o[2 * j]), __float2half(o[2 * j + 1]));
        } else {
            const float* lp = loc + (size_t)node * F_LOC + (l8 - 6) * 8;
            float4 f0 = reinterpret_cast<const float4*>(lp)[0];
            float4 f1 = reinterpret_cast<const float4*>(lp)[1];
            q[0] = __halves2half2(__float2half(f0.x), __float2half(f0.y));
            q[1] = __halves2half2(__float2half(f0.z), __float2half(f0.w));
            q[2] = __halves2half2(__float2half(f1.x), __float2half(f1.y));
            q[3] = __halves2half2(__float2half(f1.z), __float2half(f1.w));
        }
        reinterpret_cast<int4*>(x1h)[(size_t)node * 8 + l8] =
            *reinterpret_cast<int4*>(q);
    }
}

// fused: agg2 + self + bias -> out (fp32)
__global__ __launch_bounds__(256) void k_out(
    const __half* __restrict__ h2h, const float* __restrict__ dinv,
    const int* __restrict__ rowptr, const unsigned* __restrict__ csr4,
    const float* __restrict__ b2, float* __restrict__ out) {
    int wave = threadIdx.x >> 6;
    int lane = threadIdx.x & 63;
    int grp = lane >> 3;
    int l8 = lane & 7;
    int node = blockIdx.x * 4 + wave;
    if (node >= N_NODES) return;
    int r0 = rowptr[node], r1 = rowptr[node + 1];
    const char* h2c = reinterpret_cast<const char*>(h2h);
    float di = dinv[node];
    int4 hs = *reinterpret_cast<const int4*>(h2c + ((size_t)node << 7) + (l8 << 4));
    int len = r1 - r0;
    int L = (len + 7) >> 3;
    int gs = r0 + grp * L;
    int ge = gs + L;
    if (ge > r1) ge = r1;
    __half2 z2 = __float2half2_rn(0.f);
    __half2 a0[4] = {z2, z2, z2, z2};
    __half2 a1[4] = {z2, z2, z2, z2};
    int e = gs;
    for (; e + 1 < ge; e += 2) {
        unsigned A = csr4[e];
        unsigned B = csr4[e + 1];
        int4 vA = *reinterpret_cast<const int4*>(h2c + ((A >> 14) << 7) + (l8 << 4));
        int4 vB = *reinterpret_cast<const int4*>(h2c + ((B >> 14) << 7) + (l8 << 4));
        fma8h(vA, c2_from(A), a0);
        fma8h(vB, c2_from(B), a1);
    }
    if (e < ge) {
        unsigned A = csr4[e];
        int4 vA = *reinterpret_cast<const int4*>(h2c + ((A >> 14) << 7) + (l8 << 4));
        fma8h(vA, c2_from(A), a0);
    }
#pragma unroll
    for (int j = 0; j < 4; ++j) a0[j] = __hadd2(a0[j], a1[j]);
#pragma unroll
    for (int j = 0; j < 4; ++j) {
        a0[j] = __hadd2(a0[j], shfl_xor_h2(a0[j], 8));
        a0[j] = __hadd2(a0[j], shfl_xor_h2(a0[j], 16));
        a0[j] = __hadd2(a0[j], shfl_xor_h2(a0[j], 32));
    }
    if (lane < 8) {
        float d2 = di * di;
        const float4* b2v = reinterpret_cast<const float4*>(b2);
        float4 bA = b2v[l8 * 2];
        float4 bB = b2v[l8 * 2 + 1];
        float bb[8] = {bA.x, bA.y, bA.z, bA.w, bB.x, bB.y, bB.z, bB.w};
        const __half2* hh = reinterpret_cast<const __half2*>(&hs);
        float o[8];
#pragma unroll
        for (int j = 0; j < 4; ++j) {
            float2 t = __half22float2(hh[j]);
            float2 ag = __half22float2(a0[j]);
            o[2 * j] = fmaf(ag.x, di, fmaf(t.x, d2, bb[2 * j]));
            o[2 * j + 1] = fmaf(ag.y, di, fmaf(t.y, d2, bb[2 * j + 1]));
        }
        float4* ov = reinterpret_cast<float4*>(out + (size_t)node * F_OUT);
        ov[l8 * 2] = make_float4(o[0], o[1], o[2], o[3]);
        ov[l8 * 2 + 1] = make_float4(o[4], o[5], o[6], o[7]);
    }
}

extern "C" void kernel_launch(void* const* d_in, const int* in_sizes, int n_in,
                              void* d_out, int out_size, void* d_ws,
                              size_t ws_size, hipStream_t stream) {
    const void* edges = d_in[0];
    const float* feat = (const float*)d_in[1];
    const float* loc = (const float*)d_in[2];
    const float* W1 = (const float*)d_in[3];
    const float* b1 = (const float*)d_in[4];
    const float* W2 = (const float*)d_in[5];
    const float* b2 = (const float*)d_in[6];
    float* out = (float*)d_out;

    char* ws = (char*)d_ws;
    float* dinv = (float*)(ws + 0);               //    400,000
    int* rowptr = (int*)(ws + 400000);            //    400,016
    int* src32 = (int*)(ws + 800016);             //  5,000,000
    int* dst32 = (int*)(ws + 5800016);            //  5,000,000
    int* bhist = (int*)(ws + 10800016);           //    156,400
    int* bsum = (int*)(ws + 10956416);            //        256
    unsigned* binned = (unsigned*)(ws + 10956672);//  5,000,000
    unsigned* csr4 = (unsigned*)(ws + 15956672);  //  5,000,000
    __half* x0h = (__half*)(ws + 20956672);       // 12,800,000 (x1h aliases)
    __half* h1h = (__half*)(ws + 33756672);       // 12,800,000
    __half* h2h = (__half*)(ws + 46556672);       // 12,800,000
    __half* wpk1 = (__half*)(ws + 59356672);      //      6,144
    __half* wpk2 = (__half*)(ws + 59362816);      //      8,192
    int* flag = (int*)(ws + 59371008);            //          4
    __half* x1h = x0h;  // safe: x0h last read by k_gemm<3,1>, before k_agg1

    k_detect<<<1, 256, 0, stream>>>((const unsigned*)edges, flag);
    k_wprep<<<1, 64, 0, stream>>>(W1, wpk1, F1, 3);
    k_wprep<<<1, 64, 0, stream>>>(W2, wpk2, F_OUT, 4);
    k_x0<<<(N_NODES * 8 + 255) / 256, 256, 0, stream>>>(feat, loc, x0h);

    // ---- CSR build: scatter-free two-level counting sort ----
    k_prepA<<<NB_BIN, 1024, 0, stream>>>(edges, flag, src32, dst32, bhist);
    k_gscan_part<<<NSCAN_PARTS, 256, 0, stream>>>(bhist, bsum, NSCAN);
    k_gscan_top<<<1, 64, 0, stream>>>(bsum, NSCAN_PARTS);
    k_gscan_down<<<NSCAN_PARTS, 256, 0, stream>>>(bhist, bsum, NSCAN);
    k_place<<<NB_BIN, 1024, 0, stream>>>(src32, dst32, bhist, binned);
    k_bucket<<<NBUK, 256, 0, stream>>>(binned, bhist, dinv, rowptr, csr4);
    k_coef<<<(N_EDGES / 4 + 255) / 256, 256, 0, stream>>>(csr4, dinv);

    // ---- GEMMs + aggregations ----
    int gblocks = (N_NODES / 32 + 3) / 4;  // 782
    k_gemm<3, 1><<<gblocks, 256, 0, stream>>>(x0h, wpk1, h1h);
    k_agg1<<<(N_NODES + 3) / 4, 256, 0, stream>>>(h1h, dinv, rowptr, csr4,
                                                  loc, b1, x1h);
    k_gemm<4, 0><<<gblocks, 256, 0, stream>>>(x1h, wpk2, h2h);
    k_out<<<(N_NODES + 3) / 4, 256, 0, stream>>>(h2h, dinv, rowptr, csr4, b2,
                                                 out);
}

// Round 11
// 165.410 us; speedup vs baseline: 1.6184x; 1.0023x over previous
//
#include <hip/hip_runtime.h>
#include <hip/hip_fp16.h>

#define N_NODES 100000
#define N_EDGES 1250000
#define F_RAW 48
#define F_LOC 16
#define F1 48
#define F_IN1 64   // F_RAW + F_LOC
#define F_IN2 64   // F1 + F_LOC
#define F_OUT 64

#define NB_BIN 100                         // edge chunks
#define CHUNK (N_EDGES / NB_BIN)           // 12500
#define NBUK 391                           // ceil(N_NODES/256) dst buckets
#define NSCAN (NBUK * NB_BIN)              // 39100
#define NSCAN_PARTS ((NSCAN + 1023) / 1024)  // 39

typedef _Float16 half8_t __attribute__((ext_vector_type(8)));
typedef float floatx4 __attribute__((ext_vector_type(4)));

// ---------------------------------------------------------------------------
// Edge-index dtype detection (int64 vs int32 buffer).
// ---------------------------------------------------------------------------
__global__ void k_detect(const unsigned* edges_u32, int* flag) {
    __shared__ int any;
    if (threadIdx.x == 0) any = 0;
    __syncthreads();
    int nz = 0;
    for (int i = threadIdx.x; i < 2048; i += 256) {
        if (edges_u32[2 * i + 1] != 0u) nz = 1;
    }
    if (nz) atomicOr(&any, 1);
    __syncthreads();
    if (threadIdx.x == 0) *flag = any;
}

__device__ __forceinline__ void load_edge(const void* edges, int is32, int e,
                                          int& s, int& d) {
    if (is32) {
        const int* p = (const int*)edges;
        s = p[e];
        d = p[N_EDGES + e];
    } else {
        const long long* p = (const long long*)edges;
        s = (int)p[e];
        d = (int)p[N_EDGES + e];
    }
}

// ---------------------------------------------------------------------------
// pass A: edges -> src32/dst32 (sequential) + per-(bucket,block) histogram.
// ---------------------------------------------------------------------------
__global__ __launch_bounds__(1024) void k_prepA(const void* edges,
                                                const int* flag,
                                                int* __restrict__ src32,
                                                int* __restrict__ dst32,
                                                int* __restrict__ bhist) {
    __shared__ int hist[NBUK];
    int b = blockIdx.x, t = threadIdx.x;
    for (int k = t; k < NBUK; k += 1024) hist[k] = 0;
    __syncthreads();
    int is32 = *flag;
    int e0 = b * CHUNK;
    int e1 = e0 + CHUNK;
    for (int e = e0 + t; e < e1; e += 1024) {
        int s, d;
        load_edge(edges, is32, e, s, d);
        src32[e] = s;
        dst32[e] = d;
        atomicAdd(&hist[d >> 8], 1);
    }
    __syncthreads();
    for (int k = t; k < NBUK; k += 1024) bhist[k * NB_BIN + b] = hist[k];
}

// ---------------------------------------------------------------------------
// generalized exclusive scan over n ints (in-place), 3 kernels.
// ---------------------------------------------------------------------------
__global__ __launch_bounds__(256) void k_gscan_part(const int* __restrict__ in,
                                                    int* __restrict__ part,
                                                    int n) {
    int b = blockIdx.x, t = threadIdx.x;
    int i0 = b * 1024 + t * 4;
    int s = 0;
#pragma unroll
    for (int j = 0; j < 4; ++j) {
        int i = i0 + j;
        if (i < n) s += in[i];
    }
#pragma unroll
    for (int m = 1; m < 64; m <<= 1) s += __shfl_xor(s, m);
    __shared__ int ws[4];
    if ((t & 63) == 0) ws[t >> 6] = s;
    __syncthreads();
    if (t == 0) part[b] = ws[0] + ws[1] + ws[2] + ws[3];
}

__global__ __launch_bounds__(64) void k_gscan_top(int* __restrict__ part,
                                                  int nb) {
    int t = threadIdx.x;
    int v = (t < nb) ? part[t] : 0;
    int x = v;
#pragma unroll
    for (int off = 1; off < 64; off <<= 1) {
        int u = __shfl_up(x, off);
        if (t >= off) x += u;
    }
    if (t < nb) part[t] = x - v;  // exclusive
}

__global__ __launch_bounds__(256) void k_gscan_down(int* __restrict__ data,
                                                    const int* __restrict__ part,
                                                    int n) {
    int b = blockIdx.x, t = threadIdx.x;
    int lane = t & 63, wv = t >> 6;
    int i0 = b * 1024 + t * 4;
    int v[4];
    int s = 0;
#pragma unroll
    for (int j = 0; j < 4; ++j) {
        int i = i0 + j;
        v[j] = (i < n) ? data[i] : 0;
        s += v[j];
    }
    int x = s;
#pragma unroll
    for (int off = 1; off < 64; off <<= 1) {
        int u = __shfl_up(x, off);
        if (lane >= off) x += u;
    }
    __shared__ int ws[4];
    if (lane == 63) ws[wv] = x;
    __syncthreads();
    int woff = 0;
    for (int w = 0; w < wv; ++w) woff += ws[w];
    int run = part[b] + woff + (x - s);
#pragma unroll
    for (int j = 0; j < 4; ++j) {
        int i = i0 + j;
        if (i < n) {
            data[i] = run;
            run += v[j];
        }
    }
}

// ---------------------------------------------------------------------------
// pass C: place edges into bucket-clustered bins. LDS slot counters only.
// binned entry = (dstlocal << 17) | src
// ---------------------------------------------------------------------------
__global__ __launch_bounds__(1024) void k_place(const int* __restrict__ src32,
                                                const int* __restrict__ dst32,
                                                const int* __restrict__ bhist,
                                                unsigned* __restrict__ binned) {
    __shared__ int cnt[NBUK];
    int b = blockIdx.x, t = threadIdx.x;
    for (int k = t; k < NBUK; k += 1024) cnt[k] = bhist[k * NB_BIN + b];
    __syncthreads();
    int e0 = b * CHUNK;
    int e1 = e0 + CHUNK;
    for (int e = e0 + t; e < e1; e += 1024) {
        int s = src32[e];
        int d = dst32[e];
        int p = atomicAdd(&cnt[d >> 8], 1);
        binned[p] = ((unsigned)(d & 255) << 17) | (unsigned)s;
    }
}

// ---------------------------------------------------------------------------
// pass D1: one block per bucket (256 nodes): dinv/rowptr + node-ordered csr4.
// ---------------------------------------------------------------------------
__global__ __launch_bounds__(256) void k_bucket(
    const unsigned* __restrict__ binned, const int* __restrict__ bhist,
    float* __restrict__ dinv, int* __restrict__ rowptr,
    unsigned* __restrict__ csr4) {
    int k = blockIdx.x, t = threadIdx.x;
    int lane = t & 63, wv = t >> 6;
    __shared__ int ldeg[256];
    __shared__ int wcnt[256];
    __shared__ int ws4[4];
    int base = bhist[k * NB_BIN];
    int next = (k + 1 < NBUK) ? bhist[(k + 1) * NB_BIN] : N_EDGES;
    int len = next - base;
    ldeg[t] = 0;
    __syncthreads();
    for (int i = t; i < len; i += 256)
        atomicAdd(&ldeg[binned[base + i] >> 17], 1);
    __syncthreads();
    int degv = ldeg[t];
    int x = degv;
#pragma unroll
    for (int off = 1; off < 64; off <<= 1) {
        int u = __shfl_up(x, off);
        if (lane >= off) x += u;
    }
    if (lane == 63) ws4[wv] = x;
    __syncthreads();
    int woff = 0;
    for (int w = 0; w < wv; ++w) woff += ws4[w];
    int excl = woff + x - degv;
    int node = k * 256 + t;
    if (node < N_NODES) {
        dinv[node] = rsqrtf((float)degv + 1.0f);
        rowptr[node] = base + excl;
    }
    wcnt[t] = base + excl;
    __syncthreads();
    for (int i = t; i < len; i += 256) {
        unsigned ent = binned[base + i];
        int dl = ent >> 17;
        int p = atomicAdd(&wcnt[dl], 1);
        csr4[p] = ent & 0x1FFFFu;
    }
    if (k == 0 && t == 0) rowptr[N_NODES] = N_EDGES;
}

// ---------------------------------------------------------------------------
// pass D2: expand csr4 (src) -> csr8 entries {byte_off = src<<7, half2 coef}.
// ---------------------------------------------------------------------------
__global__ __launch_bounds__(256) void k_csr8(const unsigned* __restrict__ csr4,
                                              const float* __restrict__ dinv,
                                              int2* __restrict__ csr8) {
    int i = blockIdx.x * 256 + threadIdx.x;
    if (i >= N_EDGES / 2) return;
    uint2 v = reinterpret_cast<const uint2*>(csr4)[i];
    unsigned h0 = (unsigned)__half_as_ushort(__float2half(dinv[v.x]));
    unsigned h1 = (unsigned)__half_as_ushort(__float2half(dinv[v.y]));
    int4 o;
    o.x = (int)(v.x << 7);
    o.y = (int)(h0 | (h0 << 16));
    o.z = (int)(v.y << 7);
    o.w = (int)(h1 | (h1 << 16));
    reinterpret_cast<int4*>(csr8)[i] = o;
}

// ---------------------------------------------------------------------------
// pack W [64][M] fp32 into MFMA B-fragment order, fp16.
// ---------------------------------------------------------------------------
__global__ void k_wprep(const float* __restrict__ W, __half* __restrict__ Wpk,
                        int M, int CT) {
    int lane = threadIdx.x;  // 64 threads
    for (int ct = 0; ct < CT; ++ct)
        for (int kt = 0; kt < 2; ++kt)
            for (int j = 0; j < 8; ++j) {
                int k = kt * 32 + (lane >> 4) * 8 + j;
                int c = ct * 16 + (lane & 15);
                Wpk[((ct * 2 + kt) * 64 + lane) * 8 + j] =
                    __float2half(W[k * M + c]);
            }
}

// ---------------------------------------------------------------------------
// GEMM1: h1 = concat(feat,loc) @ W1, reading fp32 inputs directly (cvt in reg).
// 32 nodes/wave, 3 col tiles, K=64; zero-pads h1 cols 48..63.
// ---------------------------------------------------------------------------
__global__ __launch_bounds__(256) void k_gemm1(const float* __restrict__ feat,
                                               const float* __restrict__ loc,
                                               const __half* __restrict__ Wpk,
                                               __half* __restrict__ Y) {
    int wid = threadIdx.x >> 6;
    int lane = threadIdx.x & 63;
    int nb = (blockIdx.x * 4 + wid) * 32;
    if (nb >= N_NODES) return;
    half8_t b[3][2];
#pragma unroll
    for (int ct = 0; ct < 3; ++ct)
#pragma unroll
        for (int kt = 0; kt < 2; ++kt)
            b[ct][kt] = *reinterpret_cast<const half8_t*>(
                Wpk + ((ct * 2 + kt) * 64 + lane) * 8);
    int r = lane & 15;
    int slot = lane >> 4;
    half8_t a[2][2];
#pragma unroll
    for (int rt = 0; rt < 2; ++rt)
#pragma unroll
        for (int kt = 0; kt < 2; ++kt) {
            int sl = kt * 4 + slot;  // 0..7 -> cols sl*8..sl*8+7
            int node = nb + rt * 16 + r;
            const float* sp = (sl < 6)
                                  ? feat + (size_t)node * F_RAW + sl * 8
                                  : loc + (size_t)node * F_LOC + (sl - 6) * 8;
            float4 f0 = reinterpret_cast<const float4*>(sp)[0];
            float4 f1 = reinterpret_cast<const float4*>(sp)[1];
            half8_t h;
            h[0] = (_Float16)f0.x;
            h[1] = (_Float16)f0.y;
            h[2] = (_Float16)f0.z;
            h[3] = (_Float16)f0.w;
            h[4] = (_Float16)f1.x;
            h[5] = (_Float16)f1.y;
            h[6] = (_Float16)f1.z;
            h[7] = (_Float16)f1.w;
            a[rt][kt] = h;
        }
    floatx4 acc[2][3];
#pragma unroll
    for (int rt = 0; rt < 2; ++rt)
#pragma unroll
        for (int ct = 0; ct < 3; ++ct) {
            floatx4 z = {0.f, 0.f, 0.f, 0.f};
            z = __builtin_amdgcn_mfma_f32_16x16x32_f16(a[rt][0], b[ct][0], z, 0, 0, 0);
            z = __builtin_amdgcn_mfma_f32_16x16x32_f16(a[rt][1], b[ct][1], z, 0, 0, 0);
            acc[rt][ct] = z;
        }
    int row0 = (lane >> 4) * 4;
    int col = lane & 15;
#pragma unroll
    for (int rt = 0; rt < 2; ++rt)
#pragma unroll
        for (int ct = 0; ct < 3; ++ct)
#pragma unroll
            for (int j = 0; j < 4; ++j) {
                int node = nb + rt * 16 + row0 + j;
                Y[(size_t)node * 64 + ct * 16 + col] = __float2half(acc[rt][ct][j]);
            }
    int node = nb + (lane & 31);
    int slotp = 6 + (lane >> 5);
    *reinterpret_cast<int4*>(Y + (size_t)node * 64 + slotp * 8) =
        make_int4(0, 0, 0, 0);
}

// ---------------------------------------------------------------------------
// GEMM2: Y = X @ W via mfma. 32 nodes/wave, 4 col tiles, K=64 (fp16 input).
// ---------------------------------------------------------------------------
__global__ __launch_bounds__(256) void k_gemm2(const __half* __restrict__ X,
                                               const __half* __restrict__ Wpk,
                                               __half* __restrict__ Y) {
    int wid = threadIdx.x >> 6;
    int lane = threadIdx.x & 63;
    int nb = (blockIdx.x * 4 + wid) * 32;
    if (nb >= N_NODES) return;
    half8_t b[4][2];
#pragma unroll
    for (int ct = 0; ct < 4; ++ct)
#pragma unroll
        for (int kt = 0; kt < 2; ++kt)
            b[ct][kt] = *reinterpret_cast<const half8_t*>(
                Wpk + ((ct * 2 + kt) * 64 + lane) * 8);
    int r = lane & 15;
    int ks = (lane >> 4) * 8;
    half8_t a[2][2];
#pragma unroll
    for (int rt = 0; rt < 2; ++rt)
#pragma unroll
        for (int kt = 0; kt < 2; ++kt)
            a[rt][kt] = *reinterpret_cast<const half8_t*>(
                X + ((size_t)(nb + rt * 16 + r) * 64 + kt * 32 + ks));
    floatx4 acc[2][4];
#pragma unroll
    for (int rt = 0; rt < 2; ++rt)
#pragma unroll
        for (int ct = 0; ct < 4; ++ct) {
            floatx4 z = {0.f, 0.f, 0.f, 0.f};
            z = __builtin_amdgcn_mfma_f32_16x16x32_f16(a[rt][0], b[ct][0], z, 0, 0, 0);
            z = __builtin_amdgcn_mfma_f32_16x16x32_f16(a[rt][1], b[ct][1], z, 0, 0, 0);
            acc[rt][ct] = z;
        }
    int row0 = (lane >> 4) * 4;
    int col = lane & 15;
#pragma unroll
    for (int rt = 0; rt < 2; ++rt)
#pragma unroll
        for (int ct = 0; ct < 4; ++ct)
#pragma unroll
            for (int j = 0; j < 4; ++j) {
                int node = nb + rt * 16 + row0 + j;
                Y[(size_t)node * 64 + ct * 16 + col] = __float2half(acc[rt][ct][j]);
            }
}

// ---------------------------------------------------------------------------
// gather helpers
// ---------------------------------------------------------------------------
__device__ __forceinline__ __half2 h2bits(int y) {
    return *reinterpret_cast<__half2*>(&y);
}

__device__ __forceinline__ void fma8h(const int4& p, __half2 c2, __half2 a[4]) {
    const __half2* h = reinterpret_cast<const __half2*>(&p);
#pragma unroll
    for (int j = 0; j < 4; ++j) a[j] = __hfma2(h[j], c2, a[j]);
}

__device__ __forceinline__ __half2 shfl_xor_h2(__half2 v, int m) {
    int i = *reinterpret_cast<int*>(&v);
    i = __shfl_xor(i, m);
    return *reinterpret_cast<__half2*>(&i);
}

// agg1: x1 = [relu(agg(h1)*di + h1*d2 + b1) (48) | loc (16)] as fp16 rows
__global__ __launch_bounds__(256) void k_agg1(
    const __half* __restrict__ h1h, const float* __restrict__ dinv,
    const int* __restrict__ rowptr, const int2* __restrict__ csr8,
    const float* __restrict__ loc, const float* __restrict__ b1,
    __half* __restrict__ x1h) {
    int wave = threadIdx.x >> 6;
    int lane = threadIdx.x & 63;
    int grp = lane >> 3;
    int l8 = lane & 7;
    int node = blockIdx.x * 4 + wave;
    if (node >= N_NODES) return;
    int r0 = rowptr[node], r1 = rowptr[node + 1];
    const char* h1l = reinterpret_cast<const char*>(h1h) + (l8 << 4);
    float di = dinv[node];
    int4 hs = *reinterpret_cast<const int4*>(h1l + ((size_t)node << 7));
    int len = r1 - r0;
    int L = (len + 7) >> 3;
    int gs = r0 + grp * L;
    int ge = gs + L;
    if (ge > r1) ge = r1;
    __half2 z2 = __float2half2_rn(0.f);
    __half2 a0[4] = {z2, z2, z2, z2};
    __half2 a1[4] = {z2, z2, z2, z2};
    int e = gs;
    for (; e + 1 < ge; e += 2) {
        int2 A = csr8[e];
        int2 B = csr8[e + 1];
        int4 vA = *reinterpret_cast<const int4*>(h1l + A.x);
        int4 vB = *reinterpret_cast<const int4*>(h1l + B.x);
        fma8h(vA, h2bits(A.y), a0);
        fma8h(vB, h2bits(B.y), a1);
    }
    if (e < ge) {
        int2 A = csr8[e];
        int4 vA = *reinterpret_cast<const int4*>(h1l + A.x);
        fma8h(vA, h2bits(A.y), a0);
    }
#pragma unroll
    for (int j = 0; j < 4; ++j) a0[j] = __hadd2(a0[j], a1[j]);
#pragma unroll
    for (int j = 0; j < 4; ++j) {
        a0[j] = __hadd2(a0[j], shfl_xor_h2(a0[j], 8));
        a0[j] = __hadd2(a0[j], shfl_xor_h2(a0[j], 16));
        a0[j] = __hadd2(a0[j], shfl_xor_h2(a0[j], 32));
    }
    if (lane < 8) {
        __half2 q[4];
        if (l8 < 6) {
            float d2 = di * di;
            const float4* b1v = reinterpret_cast<const float4*>(b1);
            float4 bA = b1v[l8 * 2];
            float4 bB = b1v[l8 * 2 + 1];
            float bb[8] = {bA.x, bA.y, bA.z, bA.w, bB.x, bB.y, bB.z, bB.w};
            const __half2* hh = reinterpret_cast<const __half2*>(&hs);
            float o[8];
#pragma unroll
            for (int j = 0; j < 4; ++j) {
                float2 t = __half22float2(hh[j]);
                float2 ag = __half22float2(a0[j]);
                o[2 * j] = fmaxf(fmaf(ag.x, di, fmaf(t.x, d2, bb[2 * j])), 0.f);
                o[2 * j + 1] =
                    fmaxf(fmaf(ag.y, di, fmaf(t.y, d2, bb[2 * j + 1])), 0.f);
            }
#pragma unroll
            for (int j = 0; j < 4; ++j)
                q[j] = __halves2half2(__float2half(o[2 * j]),
                                      __float2half(o[2 * j + 1]));
        } else {
            const float* lp = loc + (size_t)node * F_LOC + (l8 - 6) * 8;
            float4 f0 = reinterpret_cast<const float4*>(lp)[0];
            float4 f1 = reinterpret_cast<const float4*>(lp)[1];
            q[0] = __halves2half2(__float2half(f0.x), __float2half(f0.y));
            q[1] = __halves2half2(__float2half(f0.z), __float2half(f0.w));
            q[2] = __halves2half2(__float2half(f1.x), __float2half(f1.y));
            q[3] = __halves2half2(__float2half(f1.z), __float2half(f1.w));
        }
        reinterpret_cast<int4*>(x1h)[(size_t)node * 8 + l8] =
            *reinterpret_cast<int4*>(q);
    }
}

// fused: agg2 + self + bias -> out (fp32)
__global__ __launch_bounds__(256) void k_out(
    const __half* __restrict__ h2h, const float* __restrict__ dinv,
    const int* __restrict__ rowptr, const int2* __restrict__ csr8,
    const float* __restrict__ b2, float* __restrict__ out) {
    int wave = threadIdx.x >> 6;
    int lane = threadIdx.x & 63;
    int grp = lane >> 3;
    int l8 = lane & 7;
    int node = blockIdx.x * 4 + wave;
    if (node >= N_NODES) return;
    int r0 = rowptr[node], r1 = rowptr[node + 1];
    const char* h2l = reinterpret_cast<const char*>(h2h) + (l8 << 4);
    float di = dinv[node];
    int4 hs = *reinterpret_cast<const int4*>(h2l + ((size_t)node << 7));
    int len = r1 - r0;
    int L = (len + 7) >> 3;
    int gs = r0 + grp * L;
    int ge = gs + L;
    if (ge > r1) ge = r1;
    __half2 z2 = __float2half2_rn(0.f);
    __half2 a0[4] = {z2, z2, z2, z2};
    __half2 a1[4] = {z2, z2, z2, z2};
    int e = gs;
    for (; e + 1 < ge; e += 2) {
        int2 A = csr8[e];
        int2 B = csr8[e + 1];
        int4 vA = *reinterpret_cast<const int4*>(h2l + A.x);
        int4 vB = *reinterpret_cast<const int4*>(h2l + B.x);
        fma8h(vA, h2bits(A.y), a0);
        fma8h(vB, h2bits(B.y), a1);
    }
    if (e < ge) {
        int2 A = csr8[e];
        int4 vA = *reinterpret_cast<const int4*>(h2l + A.x);
        fma8h(vA, h2bits(A.y), a0);
    }
#pragma unroll
    for (int j = 0; j < 4; ++j) a0[j] = __hadd2(a0[j], a1[j]);
#pragma unroll
    for (int j = 0; j < 4; ++j) {
        a0[j] = __hadd2(a0[j], shfl_xor_h2(a0[j], 8));
        a0[j] = __hadd2(a0[j], shfl_xor_h2(a0[j], 16));
        a0[j] = __hadd2(a0[j], shfl_xor_h2(a0[j], 32));
    }
    if (lane < 8) {
        float d2 = di * di;
        const float4* b2v = reinterpret_cast<const float4*>(b2);
        float4 bA = b2v[l8 * 2];
        float4 bB = b2v[l8 * 2 + 1];
        float bb[8] = {bA.x, bA.y, bA.z, bA.w, bB.x, bB.y, bB.z, bB.w};
        const __half2* hh = reinterpret_cast<const __half2*>(&hs);
        float o[8];
#pragma unroll
        for (int j = 0; j < 4; ++j) {
            float2 t = __half22float2(hh[j]);
            float2 ag = __half22float2(a0[j]);
            o[2 * j] = fmaf(ag.x, di, fmaf(t.x, d2, bb[2 * j]));
            o[2 * j + 1] = fmaf(ag.y, di, fmaf(t.y, d2, bb[2 * j + 1]));
        }
        float4* ov = reinterpret_cast<float4*>(out + (size_t)node * F_OUT);
        ov[l8 * 2] = make_float4(o[0], o[1], o[2], o[3]);
        ov[l8 * 2 + 1] = make_float4(o[4], o[5], o[6], o[7]);
    }
}

extern "C" void kernel_launch(void* const* d_in, const int* in_sizes, int n_in,
                              void* d_out, int out_size, void* d_ws,
                              size_t ws_size, hipStream_t stream) {
    const void* edges = d_in[0];
    const float* feat = (const float*)d_in[1];
    const float* loc = (const float*)d_in[2];
    const float* W1 = (const float*)d_in[3];
    const float* b1 = (const float*)d_in[4];
    const float* W2 = (const float*)d_in[5];
    const float* b2 = (const float*)d_in[6];
    float* out = (float*)d_out;

    char* ws = (char*)d_ws;
    float* dinv = (float*)(ws + 0);               //    400,000
    int* rowptr = (int*)(ws + 400000);            //    400,016
    int* src32 = (int*)(ws + 800016);             //  5,000,000 \ csr8 overlays
    int* dst32 = (int*)(ws + 5800016);            //  5,000,000 / (dead after place)
    int* bhist = (int*)(ws + 10800016);           //    156,400
    int* bsum = (int*)(ws + 10956416);            //        256
    unsigned* binned = (unsigned*)(ws + 10956672);//  5,000,000
    unsigned* csr4 = (unsigned*)(ws + 15956672);  //  5,000,000
    __half* x1h = (__half*)(ws + 20956672);       // 12,800,000
    __half* h1h = (__half*)(ws + 33756672);       // 12,800,000
    __half* h2h = (__half*)(ws + 46556672);       // 12,800,000
    __half* wpk1 = (__half*)(ws + 59356672);      //      6,144
    __half* wpk2 = (__half*)(ws + 59362816);      //      8,192
    int* flag = (int*)(ws + 59371008);            //          4
    int2* csr8 = (int2*)(ws + 800016);            // 10,000,000 (over src/dst32)

    k_detect<<<1, 256, 0, stream>>>((const unsigned*)edges, flag);
    k_wprep<<<1, 64, 0, stream>>>(W1, wpk1, F1, 3);
    k_wprep<<<1, 64, 0, stream>>>(W2, wpk2, F_OUT, 4);

    // ---- CSR build: scatter-free two-level counting sort ----
    k_prepA<<<NB_BIN, 1024, 0, stream>>>(edges, flag, src32, dst32, bhist);
    k_gscan_part<<<NSCAN_PARTS, 256, 0, stream>>>(bhist, bsum, NSCAN);
    k_gscan_top<<<1, 64, 0, stream>>>(bsum, NSCAN_PARTS);
    k_gscan_down<<<NSCAN_PARTS, 256, 0, stream>>>(bhist, bsum, NSCAN);
    k_place<<<NB_BIN, 1024, 0, stream>>>(src32, dst32, bhist, binned);
    k_bucket<<<NBUK, 256, 0, stream>>>(binned, bhist, dinv, rowptr, csr4);
    k_csr8<<<(N_EDGES / 2 + 255) / 256, 256, 0, stream>>>(csr4, dinv, csr8);

    // ---- GEMMs + aggregations ----
    int gblocks = (N_NODES / 32 + 3) / 4;  // 782
    k_gemm1<<<gblocks, 256, 0, stream>>>(feat, loc, wpk1, h1h);
    k_agg1<<<(N_NODES + 3) / 4, 256, 0, stream>>>(h1h, dinv, rowptr, csr8,
                                                  loc, b1, x1h);
    k_gemm2<<<gblocks, 256, 0, stream>>>(x1h, wpk2, h2h);
    k_out<<<(N_NODES + 3) / 4, 256, 0, stream>>>(h2h, dinv, rowptr, csr8, b2,
                                                 out);
}